// Round 14
// baseline (552.879 us; speedup 1.0000x reference)
//
#include <hip/hip_runtime.h>
#include <hip/hip_bf16.h>

// Attention: B=512, T=128, C=512, H=64. out[b,t,h] f32.
// R14: AMPLIFIED ABLATION. Each variant repeats its phase REP times inside
// one dispatch so it exceeds the ~76us poison-fills and shows up in the
// rocprof top-5 with its own counters.
//   V1 x12 = staging skeleton (gload_lds + barriers + counted vmcnt)
//   V2 x6  = staging + projection compute (acc kept live via asm sink)
//   V4 x12 = projection compute only (LDS garbage, opaque addrs, no barriers)
//   V3 x12 = attention phases only (LDS garbage, no global stores)
//   V0 x1  = full kernel, launched last -> correct d_out.

#define TT 128
#define CC 512
#define HH 64

typedef __attribute__((ext_vector_type(8))) short bf16x8;
typedef __attribute__((ext_vector_type(4))) float f32x4;

__device__ __forceinline__ ushort f2bf(float f) {
    union { float f; unsigned u; } v; v.f = f;
    unsigned r = v.u + 0x7fffu + ((v.u >> 16) & 1u);  // RNE
    return (ushort)(r >> 16);
}

__device__ __forceinline__ void gload_lds16(const void* g, void* l) {
    __builtin_amdgcn_global_load_lds(
        (const __attribute__((address_space(1))) unsigned int*)g,
        (__attribute__((address_space(3))) unsigned int*)l, 16, 0, 0);
}

// ---- wpack: chunk kt stride 8192 ushorts (16KB, last 4KB pad unused) ----
__global__ void wpack_kernel(const float* __restrict__ wq,
                             const float* __restrict__ wk,
                             const float* __restrict__ wv,
                             ushort* __restrict__ wpk) {
    int p = blockIdx.x * 256 + threadIdx.x;   // 0..98303
    int j  = p & 7;
    int l  = (p >> 3) & 63;
    int nt = (p >> 9) % 12;
    int kt = p / (12 * 512);
    int w  = nt >> 2;
    const float* src = (w == 0) ? wq : ((w == 1) ? wk : wv);
    int h = (nt & 3) * 16 + (l & 15);
    int c = kt * 32 + ((l >> 4) << 3) + j;
    wpk[kt * 8192 + ((nt * 64 + l) * 8) + j] = f2bf(src[h * 512 + c]);
}

template<int V, int REP>
__launch_bounds__(512, 4)
__global__ void abl_kernel(const float* __restrict__ x,
                           const ushort* __restrict__ wpk,
                           float* __restrict__ out,
                           float* __restrict__ scratch) {
    __shared__ __align__(16) char smem[65536];
    ushort* qs  = (ushort*)smem;
    ushort* ks  = (ushort*)(smem + 16384);
    ushort* vst = (ushort*)(smem + 32768);
    ushort* ps  = (ushort*)smem;

    const int tid  = threadIdx.x;
    const int wave = tid >> 6;
    const int lane = tid & 63;
    const int lq   = lane >> 4;
    const int lr   = lane & 15;
    const int b    = blockIdx.x;
    const size_t bB = (size_t)b * TT;

    const f32x4 fzero = {0.f, 0.f, 0.f, 0.f};
    const int r = wave * 16 + lr;

    auto stage = [&](int kt, int s) {
        const char* wsrc = (const char*)(wpk + kt * 8192);
        char* wdst = smem + s * 16384;
        #pragma unroll
        for (int p = 0; p < 2; ++p) {
            int off = wave * 2048 + p * 1024;
            gload_lds16(wsrc + off + lane * 16, wdst + off);
        }
        char* xdst = smem + 32768 + s * 16384;
        #pragma unroll
        for (int p = 0; p < 2; ++p) {
            int uoff = wave * 2048 + p * 1024;
            int off  = uoff + lane * 16;
            int row  = off >> 7;
            int slot = (off >> 4) & 7;
            int g    = slot ^ (row & 7);
            const float* src = x + (bB + row) * CC + kt * 32 + g * 4;
            gload_lds16(src, xdst + uoff);
        }
    };

    f32x4 acc[12];
    #pragma unroll
    for (int j = 0; j < 12; ++j) acc[j] = fzero;

    if constexpr (V == 0 || V == 1 || V == 2) {
        for (int rep = 0; rep < REP; ++rep) {
            #pragma unroll
            for (int j = 0; j < 12; ++j) acc[j] = fzero;
            stage(0, 0);
            for (int kt = 0; kt < 16; ++kt) {
                const int cur = kt & 1;
                __builtin_amdgcn_s_barrier();
                if (kt + 1 < 16) {
                    stage(kt + 1, cur ^ 1);
                    asm volatile("s_waitcnt vmcnt(4)" ::: "memory");
                } else {
                    asm volatile("s_waitcnt vmcnt(0)" ::: "memory");
                }
                __builtin_amdgcn_sched_barrier(0);
                __builtin_amdgcn_s_barrier();
                __builtin_amdgcn_sched_barrier(0);

                if constexpr (V != 1) {
                    const float* xs = (const float*)(smem + 32768 + cur * 16384);
                    int s0 = (lq * 2) ^ (r & 7);
                    int s1 = (lq * 2 + 1) ^ (r & 7);
                    f32x4 alo = *(const f32x4*)(xs + r * 32 + s0 * 4);
                    f32x4 ahi = *(const f32x4*)(xs + r * 32 + s1 * 4);
                    const ushort* wf = (const ushort*)(smem + cur * 16384);
                    bf16x8 w[12];
                    #pragma unroll
                    for (int nt = 0; nt < 12; ++nt)
                        w[nt] = *(const bf16x8*)(wf + (nt * 64 + lane) * 8);
                    bf16x8 a;
                    a[0] = (short)f2bf(alo[0]); a[1] = (short)f2bf(alo[1]);
                    a[2] = (short)f2bf(alo[2]); a[3] = (short)f2bf(alo[3]);
                    a[4] = (short)f2bf(ahi[0]); a[5] = (short)f2bf(ahi[1]);
                    a[6] = (short)f2bf(ahi[2]); a[7] = (short)f2bf(ahi[3]);
                    #pragma unroll
                    for (int nt = 0; nt < 12; ++nt)
                        acc[nt] = __builtin_amdgcn_mfma_f32_16x16x32_bf16(a, w[nt], acc[nt], 0, 0, 0);
                }
            }
            if constexpr (V == 2) {
                float sv = 0.f;
                #pragma unroll
                for (int nt = 0; nt < 12; ++nt)
                    #pragma unroll
                    for (int j = 0; j < 4; ++j) sv += acc[nt][j];
                asm volatile("" :: "v"(sv));           // keep chain live
            }
        }
        if constexpr (V == 1) { if (tid == 0) scratch[b] = 1.f; return; }
        if constexpr (V == 2) { if (tid == 0) scratch[b] = 2.f; return; }
    }

    if constexpr (V == 4) {
        // pure compute pipe: same reads/pack/MFMA, garbage LDS, no barriers.
        for (int rep = 0; rep < REP; ++rep) {
            #pragma unroll
            for (int j = 0; j < 12; ++j) acc[j] = fzero;
            for (int kt = 0; kt < 16; ++kt) {
                unsigned xb = 32768u + (kt & 1) * 16384u;
                unsigned wb = (kt & 1) * 16384u;
                asm volatile("" : "+v"(xb));           // opaque: no CSE/hoist
                asm volatile("" : "+v"(wb));
                const float* xs = (const float*)(smem + xb);
                const ushort* wf = (const ushort*)(smem + wb);
                int s0 = (lq * 2) ^ (r & 7);
                int s1 = (lq * 2 + 1) ^ (r & 7);
                f32x4 alo = *(const f32x4*)(xs + r * 32 + s0 * 4);
                f32x4 ahi = *(const f32x4*)(xs + r * 32 + s1 * 4);
                bf16x8 w[12];
                #pragma unroll
                for (int nt = 0; nt < 12; ++nt)
                    w[nt] = *(const bf16x8*)(wf + (nt * 64 + lane) * 8);
                bf16x8 a;
                a[0] = (short)f2bf(alo[0]); a[1] = (short)f2bf(alo[1]);
                a[2] = (short)f2bf(alo[2]); a[3] = (short)f2bf(alo[3]);
                a[4] = (short)f2bf(ahi[0]); a[5] = (short)f2bf(ahi[1]);
                a[6] = (short)f2bf(ahi[2]); a[7] = (short)f2bf(ahi[3]);
                #pragma unroll
                for (int nt = 0; nt < 12; ++nt)
                    acc[nt] = __builtin_amdgcn_mfma_f32_16x16x32_bf16(a, w[nt], acc[nt], 0, 0, 0);
            }
            float sv = 0.f;
            #pragma unroll
            for (int nt = 0; nt < 12; ++nt)
                #pragma unroll
                for (int j = 0; j < 4; ++j) sv += acc[nt][j];
            asm volatile("" :: "v"(sv));
        }
        if (tid == 0) scratch[b] = 4.f;
        return;
    }

    if constexpr (V == 0) {
        __syncthreads();
        #pragma unroll
        for (int nt = 0; nt < 12; ++nt)
            #pragma unroll
            for (int j = 0; j < 4; ++j) {
                int t = wave * 16 + lq * 4 + j;
                int h = (nt & 3) * 16 + lr;
                ushort v = f2bf(acc[nt][j]);
                if (nt < 4)      qs[t * 64 + (h ^ ((t & 7) << 3))] = v;
                else if (nt < 8) ks[t * 64 + (h ^ ((t & 7) << 3))] = v;
                else             vst[h * 128 + (t ^ ((h & 7) << 3))] = v;
            }
    }

    // ---- attention phases (V0 and V3) ----
    const int row0 = wave * 16;
    for (int rep = 0; rep < (V == 3 ? REP : 1); ++rep) {
        __syncthreads();
        f32x4 s[8];
        #pragma unroll
        for (int j = 0; j < 8; ++j) s[j] = fzero;

        #pragma unroll
        for (int kt = 0; kt < 2; ++kt) {
            int h0 = kt * 32 + lq * 8;
            int t  = row0 + lr;
            bf16x8 a = *(const bf16x8*)&qs[t * 64 + (h0 ^ ((t & 7) << 3))];
            bf16x8 kf[8];
            #pragma unroll
            for (int nt = 0; nt < 8; ++nt) {
                int sc = nt * 16 + lr;
                kf[nt] = *(const bf16x8*)&ks[sc * 64 + (h0 ^ ((sc & 7) << 3))];
            }
            #pragma unroll
            for (int nt = 0; nt < 8; ++nt)
                s[nt] = __builtin_amdgcn_mfma_f32_16x16x32_bf16(a, kf[nt], s[nt], 0, 0, 0);
        }

        float rinv[4];
        #pragma unroll
        for (int j = 0; j < 4; ++j) {
            int t = row0 + lq * 4 + j;
            float m = -1e30f;
            #pragma unroll
            for (int nt = 0; nt < 8; ++nt) {
                int sc = nt * 16 + lr;
                float v = s[nt][j] * 0.125f;
                v = (sc <= t) ? v : -1e30f;
                s[nt][j] = v;
                m = fmaxf(m, v);
            }
            m = fmaxf(m, __shfl_xor(m, 1));
            m = fmaxf(m, __shfl_xor(m, 2));
            m = fmaxf(m, __shfl_xor(m, 4));
            m = fmaxf(m, __shfl_xor(m, 8));
            float sum = 0.f;
            #pragma unroll
            for (int nt = 0; nt < 8; ++nt) {
                float p = __expf(s[nt][j] - m);
                s[nt][j] = p;
                sum += p;
            }
            sum += __shfl_xor(sum, 1);
            sum += __shfl_xor(sum, 2);
            sum += __shfl_xor(sum, 4);
            sum += __shfl_xor(sum, 8);
            rinv[j] = 1.0f / sum;
        }

        __syncthreads();
        #pragma unroll
        for (int j = 0; j < 4; ++j) {
            int t = row0 + lq * 4 + j;
            #pragma unroll
            for (int nt = 0; nt < 8; ++nt) {
                int sc = nt * 16 + lr;
                ps[t * 128 + (sc ^ ((t & 7) << 3))] = f2bf(s[nt][j]);
            }
        }
        __syncthreads();

        f32x4 o[4];
        #pragma unroll
        for (int j = 0; j < 4; ++j) o[j] = fzero;
        #pragma unroll
        for (int ksv = 0; ksv < 4; ++ksv) {
            int s0 = ksv * 32 + lq * 8;
            int t  = row0 + lr;
            bf16x8 a = *(const bf16x8*)&ps[t * 128 + (s0 ^ ((t & 7) << 3))];
            bf16x8 vf[4];
            #pragma unroll
            for (int nt = 0; nt < 4; ++nt) {
                int h = nt * 16 + lr;
                vf[nt] = *(const bf16x8*)&vst[h * 128 + (s0 ^ ((h & 7) << 3))];
            }
            #pragma unroll
            for (int nt = 0; nt < 4; ++nt)
                o[nt] = __builtin_amdgcn_mfma_f32_16x16x32_bf16(a, vf[nt], o[nt], 0, 0, 0);
        }

        if constexpr (V == 3) {
            float sv = 0.f;
            #pragma unroll
            for (int nt = 0; nt < 4; ++nt)
                #pragma unroll
                for (int j = 0; j < 4; ++j) sv += o[nt][j] * rinv[j];
            asm volatile("" :: "v"(sv));
        } else {
            float* ob = out + (size_t)b * (TT * HH);
            #pragma unroll
            for (int nt = 0; nt < 4; ++nt)
                #pragma unroll
                for (int j = 0; j < 4; ++j) {
                    int t = row0 + lq * 4 + j;
                    int h = nt * 16 + lr;
                    ob[t * HH + h] = o[nt][j] * rinv[j];
                }
        }
    }
    if constexpr (V == 3) { if (tid == 0) scratch[b] = 3.f; }
}

extern "C" void kernel_launch(void* const* d_in, const int* in_sizes, int n_in,
                              void* d_out, int out_size, void* d_ws, size_t ws_size,
                              hipStream_t stream) {
    const float* x  = (const float*)d_in[0];
    const float* wq = (const float*)d_in[1];
    const float* wk = (const float*)d_in[2];
    const float* wv = (const float*)d_in[3];
    float* o = (float*)d_out;
    ushort* wpk = (ushort*)d_ws;                        // 256 KB packed W
    float* scratch = (float*)((char*)d_ws + 262144);

    (void)in_sizes; (void)n_in; (void)out_size; (void)ws_size;

    wpack_kernel<<<384, 256, 0, stream>>>(wq, wk, wv, wpk);
    abl_kernel<1, 12><<<512, 512, 0, stream>>>(x, wpk, o, scratch);
    abl_kernel<4, 12><<<512, 512, 0, stream>>>(x, wpk, o, scratch);
    abl_kernel<2, 6><<<512, 512, 0, stream>>>(x, wpk, o, scratch);
    abl_kernel<3, 12><<<512, 512, 0, stream>>>(x, wpk, o, scratch);
    abl_kernel<0, 1><<<512, 512, 0, stream>>>(x, wpk, o, scratch);
}

// Round 15
// 39.385 us; speedup vs baseline: 14.0377x; 14.0377x over previous
//
#include <hip/hip_runtime.h>
#include <hip/hip_bf16.h>

// Attention: B=512, T=128, C=512, H=64. out[b,t,h] f32.
// R15: 3-deep staging pipeline. R14's ablation showed the 2-buffer staging
// skeleton ALONE costs ~20.6us/rep (60% of kernel) at 3.4TB/s with all
// pipes idle -> per-iteration exposed memory latency is the wall (m233:
// 2-phase stall is structural). Fix: W staged into 3 rotating LDS buffers
// with stage(kt+2) issued at iter kt (2 iterations of flight), x loaded
// 2 iterations ahead into 3 rotating register slots (never touches LDS).
// vmcnt ladder: 6 / 8... / 4 / 0. Attention phases unchanged.

#define TT 128
#define CC 512
#define HH 64

typedef __attribute__((ext_vector_type(8))) short bf16x8;
typedef __attribute__((ext_vector_type(4))) float f32x4;

__device__ __forceinline__ ushort f2bf(float f) {
    union { float f; unsigned u; } v; v.f = f;
    unsigned r = v.u + 0x7fffu + ((v.u >> 16) & 1u);  // RNE
    return (ushort)(r >> 16);
}

__device__ __forceinline__ void gload_lds16(const void* g, void* l) {
    __builtin_amdgcn_global_load_lds(
        (const __attribute__((address_space(1))) unsigned int*)g,
        (__attribute__((address_space(3))) unsigned int*)l, 16, 0, 0);
}

// ---- wpack: chunk kt stride 8192 ushorts (16KB, last 4KB pad unused) ----
// idx = kt*8192 + (nt*64+lane)*8 + j ; value = W_{nt>>2}[h][c],
// h = (nt&3)*16 + (lane&15), c = kt*32 + (lane>>4)*8 + j
__global__ void wpack_kernel(const float* __restrict__ wq,
                             const float* __restrict__ wk,
                             const float* __restrict__ wv,
                             ushort* __restrict__ wpk) {
    int p = blockIdx.x * 256 + threadIdx.x;   // 0..98303
    int j  = p & 7;
    int l  = (p >> 3) & 63;
    int nt = (p >> 9) % 12;
    int kt = p / (12 * 512);
    int w  = nt >> 2;
    const float* src = (w == 0) ? wq : ((w == 1) ? wk : wv);
    int h = (nt & 3) * 16 + (l & 15);
    int c = kt * 32 + ((l >> 4) << 3) + j;
    wpk[kt * 8192 + ((nt * 64 + l) * 8) + j] = f2bf(src[h * 512 + c]);
}

// ---- fused: one block per batch element; 8 waves; 512 blocks ----
__launch_bounds__(512, 4)
__global__ void attn_fused_kernel(const float* __restrict__ x,
                                  const ushort* __restrict__ wpk,
                                  float* __restrict__ out) {
    // 48 KB LDS. staging: 3 W buffers @ 0/16K/32K (12KB data + 4KB pad each).
    // attention: qs @0, ks @16K, vst @32K; ps = [0,32K) overlay.
    __shared__ __align__(16) char smem[49152];
    ushort* qs  = (ushort*)smem;               // [128][64] swizzled col^((t&7)<<3)
    ushort* ks  = (ushort*)(smem + 16384);     // [128][64] swizzled
    ushort* vst = (ushort*)(smem + 32768);     // [64][128] V^T, swizzled t^((h&7)<<3)
    ushort* ps  = (ushort*)smem;               // [128][128] P overlay, swizzled

    const int tid  = threadIdx.x;
    const int wave = tid >> 6;
    const int lane = tid & 63;
    const int lq   = lane >> 4;
    const int lr   = lane & 15;
    const int b    = blockIdx.x;
    const size_t bB = (size_t)b * TT;

    const f32x4 fzero = {0.f, 0.f, 0.f, 0.f};

    // ================= Phase 1: QKV projection (16 chunks of K=32) ========
    f32x4 acc[12];
    #pragma unroll
    for (int j = 0; j < 12; ++j) acc[j] = fzero;

    const int r = wave * 16 + lr;                  // block-local row
    const float* xr = x + (bB + r) * CC + lq * 8;  // lane's x base (col lq*8)

    // W chunk kt (16KB incl pad) -> LDS buf s; 2 x 1KB gload_lds per wave
    auto stageW = [&](int kt, int s) {
        const char* wsrc = (const char*)wpk + kt * 16384;
        char* wdst = smem + s * 16384;
        #pragma unroll
        for (int p = 0; p < 2; ++p) {
            int off = wave * 2048 + p * 1024;
            gload_lds16(wsrc + off + lane * 16, wdst + off);
        }
    };

    // x chunk kt -> 2 dwordx4 (one row, 8 floats) via volatile asm so the
    // prefetch cannot be folded; our manual vmcnt ladder covers the hazard.
    #define LOADX(kt, dlo, dhi)                                                \
        {                                                                      \
            const float* p0 = xr + (kt) * 32;                                  \
            asm volatile("global_load_dwordx4 %0, %1, off"                     \
                         : "=&v"(dlo) : "v"(p0) : "memory");                   \
            asm volatile("global_load_dwordx4 %0, %1, off offset:16"           \
                         : "=&v"(dhi) : "v"(p0) : "memory");                   \
        }

    f32x4 x0a, x0b, x1a, x1b, x2a, x2b;   // 3 rotating slots

    // prologue: W0,W1 staged; x0,x1 issued   (order: W0 W1 x0 x1)
    stageW(0, 0);
    stageW(1, 1);
    LOADX(0, x0a, x0b);
    LOADX(1, x1a, x1b);

    #pragma unroll
    for (int kt = 0; kt < 16; ++kt) {
        const int cur = kt % 3;

        // barrier 1: all waves finished iter kt-1 -> buf (kt+2)%3 (last read
        // at iter kt-1) is safe to overwrite.
        __builtin_amdgcn_s_barrier();

        if (kt + 2 < 16) {
            stageW(kt + 2, (kt + 2) % 3);          // 2 ops
            const int slot = (kt + 2) % 3;         // 2 ops
            if (slot == 0)      LOADX(kt + 2, x0a, x0b)
            else if (slot == 1) LOADX(kt + 2, x1a, x1b)
            else                LOADX(kt + 2, x2a, x2b)
        }

        // wait for x(kt) (and W(kt), which is older): loads issued 2 iters ago
        if (kt == 0)       asm volatile("s_waitcnt vmcnt(6)" ::: "memory");
        else if (kt <= 13) asm volatile("s_waitcnt vmcnt(8)" ::: "memory");
        else if (kt == 14) asm volatile("s_waitcnt vmcnt(4)" ::: "memory");
        else               asm volatile("s_waitcnt vmcnt(0)" ::: "memory");
        __builtin_amdgcn_sched_barrier(0);

        // barrier 2: every wave's W(kt) slice visible in LDS.
        __builtin_amdgcn_s_barrier();
        __builtin_amdgcn_sched_barrier(0);

        // pack this chunk's A fragment from the register slot
        f32x4 alo, ahi;
        if (cur == 0)      { alo = x0a; ahi = x0b; }
        else if (cur == 1) { alo = x1a; ahi = x1b; }
        else               { alo = x2a; ahi = x2b; }
        bf16x8 a;
        a[0] = (short)f2bf(alo[0]); a[1] = (short)f2bf(alo[1]);
        a[2] = (short)f2bf(alo[2]); a[3] = (short)f2bf(alo[3]);
        a[4] = (short)f2bf(ahi[0]); a[5] = (short)f2bf(ahi[1]);
        a[6] = (short)f2bf(ahi[2]); a[7] = (short)f2bf(ahi[3]);

        const ushort* wf = (const ushort*)(smem + cur * 16384);
        #pragma unroll
        for (int g = 0; g < 3; ++g) {
            bf16x8 w0 = *(const bf16x8*)(wf + ((g * 4 + 0) * 64 + lane) * 8);
            bf16x8 w1 = *(const bf16x8*)(wf + ((g * 4 + 1) * 64 + lane) * 8);
            bf16x8 w2 = *(const bf16x8*)(wf + ((g * 4 + 2) * 64 + lane) * 8);
            bf16x8 w3 = *(const bf16x8*)(wf + ((g * 4 + 3) * 64 + lane) * 8);
            acc[g * 4 + 0] = __builtin_amdgcn_mfma_f32_16x16x32_bf16(a, w0, acc[g * 4 + 0], 0, 0, 0);
            acc[g * 4 + 1] = __builtin_amdgcn_mfma_f32_16x16x32_bf16(a, w1, acc[g * 4 + 1], 0, 0, 0);
            acc[g * 4 + 2] = __builtin_amdgcn_mfma_f32_16x16x32_bf16(a, w2, acc[g * 4 + 2], 0, 0, 0);
            acc[g * 4 + 3] = __builtin_amdgcn_mfma_f32_16x16x32_bf16(a, w3, acc[g * 4 + 3], 0, 0, 0);
        }
    }

    __syncthreads();   // compute(15) done everywhere before overlay writes

    // ---- QKV -> attention LDS (overlays staging buffers) ----
    #pragma unroll
    for (int nt = 0; nt < 12; ++nt)
        #pragma unroll
        for (int j = 0; j < 4; ++j) {
            int t = wave * 16 + lq * 4 + j;
            int h = (nt & 3) * 16 + lr;
            ushort v = f2bf(acc[nt][j]);
            if (nt < 4)      qs[t * 64 + (h ^ ((t & 7) << 3))] = v;
            else if (nt < 8) ks[t * 64 + (h ^ ((t & 7) << 3))] = v;
            else             vst[h * 128 + (t ^ ((h & 7) << 3))] = v;
        }
    __syncthreads();

    // ================= Phase 2: S = Q K^T, causal softmax =================
    const int row0 = wave * 16;
    f32x4 s[8];
    #pragma unroll
    for (int j = 0; j < 8; ++j) s[j] = fzero;

    #pragma unroll
    for (int kt = 0; kt < 2; ++kt) {
        int h0 = kt * 32 + lq * 8;
        int t  = row0 + lr;
        bf16x8 a = *(const bf16x8*)&qs[t * 64 + (h0 ^ ((t & 7) << 3))];
        bf16x8 kf[8];
        #pragma unroll
        for (int nt = 0; nt < 8; ++nt) {
            int sc = nt * 16 + lr;
            kf[nt] = *(const bf16x8*)&ks[sc * 64 + (h0 ^ ((sc & 7) << 3))];
        }
        #pragma unroll
        for (int nt = 0; nt < 8; ++nt)
            s[nt] = __builtin_amdgcn_mfma_f32_16x16x32_bf16(a, kf[nt], s[nt], 0, 0, 0);
    }

    float rinv[4];
    #pragma unroll
    for (int j = 0; j < 4; ++j) {
        int t = row0 + lq * 4 + j;
        float m = -1e30f;
        #pragma unroll
        for (int nt = 0; nt < 8; ++nt) {
            int sc = nt * 16 + lr;
            float v = s[nt][j] * 0.125f;
            v = (sc <= t) ? v : -1e30f;        // causal mask
            s[nt][j] = v;
            m = fmaxf(m, v);
        }
        m = fmaxf(m, __shfl_xor(m, 1));
        m = fmaxf(m, __shfl_xor(m, 2));
        m = fmaxf(m, __shfl_xor(m, 4));
        m = fmaxf(m, __shfl_xor(m, 8));
        float sum = 0.f;
        #pragma unroll
        for (int nt = 0; nt < 8; ++nt) {
            float p = __expf(s[nt][j] - m);
            s[nt][j] = p;
            sum += p;
        }
        sum += __shfl_xor(sum, 1);
        sum += __shfl_xor(sum, 2);
        sum += __shfl_xor(sum, 4);
        sum += __shfl_xor(sum, 8);
        rinv[j] = 1.0f / sum;                  // deferred normalization
    }

    __syncthreads();   // all qs/ks reads done before P overlay writes

    #pragma unroll
    for (int j = 0; j < 4; ++j) {
        int t = row0 + lq * 4 + j;
        #pragma unroll
        for (int nt = 0; nt < 8; ++nt) {
            int sc = nt * 16 + lr;
            ps[t * 128 + (sc ^ ((t & 7) << 3))] = f2bf(s[nt][j]);
        }
    }
    __syncthreads();

    // ================= Phase 3: O = P V =================
    f32x4 o[4];
    #pragma unroll
    for (int j = 0; j < 4; ++j) o[j] = fzero;

    #pragma unroll
    for (int ksv = 0; ksv < 4; ++ksv) {
        int s0 = ksv * 32 + lq * 8;
        int t  = row0 + lr;
        bf16x8 a = *(const bf16x8*)&ps[t * 128 + (s0 ^ ((t & 7) << 3))];
        bf16x8 vf[4];
        #pragma unroll
        for (int nt = 0; nt < 4; ++nt) {
            int h = nt * 16 + lr;
            vf[nt] = *(const bf16x8*)&vst[h * 128 + (s0 ^ ((h & 7) << 3))];
        }
        #pragma unroll
        for (int nt = 0; nt < 4; ++nt)
            o[nt] = __builtin_amdgcn_mfma_f32_16x16x32_bf16(a, vf[nt], o[nt], 0, 0, 0);
    }

    float* ob = out + (size_t)b * (TT * HH);
    #pragma unroll
    for (int nt = 0; nt < 4; ++nt)
        #pragma unroll
        for (int j = 0; j < 4; ++j) {
            int t = row0 + lq * 4 + j;
            int h = nt * 16 + lr;
            ob[t * HH + h] = o[nt][j] * rinv[j];
        }
}

extern "C" void kernel_launch(void* const* d_in, const int* in_sizes, int n_in,
                              void* d_out, int out_size, void* d_ws, size_t ws_size,
                              hipStream_t stream) {
    const float* x  = (const float*)d_in[0];
    const float* wq = (const float*)d_in[1];
    const float* wk = (const float*)d_in[2];
    const float* wv = (const float*)d_in[3];
    float* o = (float*)d_out;
    ushort* wpk = (ushort*)d_ws;    // 16 chunks x 16KB = 256 KB packed W

    (void)in_sizes; (void)n_in; (void)out_size; (void)ws_size;

    wpack_kernel<<<384, 256, 0, stream>>>(wq, wk, wv, wpk);
    attn_fused_kernel<<<512, 512, 0, stream>>>(x, wpk, o);
}

// Round 16
// 39.269 us; speedup vs baseline: 14.0794x; 1.0030x over previous
//
#include <hip/hip_runtime.h>
#include <hip/hip_bf16.h>

// Attention: B=512, T=128, C=512, H=64. out[b,t,h] f32.
// R16: projection kept (R14 ablation: staging = x-read BW floor ~21us);
// serial attention tail restructured:
//  - LDS 80KB: W dbuf [0,32K); qs[32K,48K) ks[48K,64K) vst[64K,80K);
//    ps overlays the dead W dbuf [0,32K). Still 2 blocks/CU (160K exact).
//  - Post-proj __syncthreads + both ps barriers removed (attn buffers are
//    virgin territory; P is wave-private -> wave-local LDS round-trip).
//  - V^T epilogue written as ds_write_b64 (4 contiguous t after swizzle).
//  - One block-wide barrier total in the attention path.

#define TT 128
#define CC 512
#define HH 64

typedef __attribute__((ext_vector_type(8))) short bf16x8;
typedef __attribute__((ext_vector_type(4))) ushort u16x4;
typedef __attribute__((ext_vector_type(4))) float f32x4;

__device__ __forceinline__ ushort f2bf(float f) {
    union { float f; unsigned u; } v; v.f = f;
    unsigned r = v.u + 0x7fffu + ((v.u >> 16) & 1u);  // RNE
    return (ushort)(r >> 16);
}

__device__ __forceinline__ void gload_lds16(const void* g, void* l) {
    __builtin_amdgcn_global_load_lds(
        (const __attribute__((address_space(1))) unsigned int*)g,
        (__attribute__((address_space(3))) unsigned int*)l, 16, 0, 0);
}

// ---- wpack: chunk kt stride 8192 ushorts (16KB, last 4KB pad unused) ----
// idx = kt*8192 + (nt*64+lane)*8 + j ; value = W_{nt>>2}[h][c],
// h = (nt&3)*16 + (lane&15), c = kt*32 + (lane>>4)*8 + j
__global__ void wpack_kernel(const float* __restrict__ wq,
                             const float* __restrict__ wk,
                             const float* __restrict__ wv,
                             ushort* __restrict__ wpk) {
    int p = blockIdx.x * 256 + threadIdx.x;   // 0..98303
    int j  = p & 7;
    int l  = (p >> 3) & 63;
    int nt = (p >> 9) % 12;
    int kt = p / (12 * 512);
    int w  = nt >> 2;
    const float* src = (w == 0) ? wq : ((w == 1) ? wk : wv);
    int h = (nt & 3) * 16 + (l & 15);
    int c = kt * 32 + ((l >> 4) << 3) + j;
    wpk[kt * 8192 + ((nt * 64 + l) * 8) + j] = f2bf(src[h * 512 + c]);
}

// ---- fused: one block per batch element; 8 waves; 512 blocks ----
__launch_bounds__(512, 4)
__global__ void attn_fused_kernel(const float* __restrict__ x,
                                  const ushort* __restrict__ wpk,
                                  float* __restrict__ out) {
    // 80 KB LDS -> 2 blocks/CU (160K exact).
    __shared__ __align__(16) char smem[81920];
    ushort* ps  = (ushort*)smem;               // [128][128] P, overlays W dbuf
    ushort* qs  = (ushort*)(smem + 32768);     // [128][64] swizzled col^((t&7)<<3)
    ushort* ks  = (ushort*)(smem + 49152);     // [128][64] swizzled
    ushort* vst = (ushort*)(smem + 65536);     // [64][128] V^T, swizzled t^((h&7)<<3)

    const int tid  = threadIdx.x;
    const int wave = tid >> 6;
    const int lane = tid & 63;
    const int lq   = lane >> 4;
    const int lr   = lane & 15;
    const int b    = blockIdx.x;
    const size_t bB = (size_t)b * TT;

    const f32x4 fzero = {0.f, 0.f, 0.f, 0.f};

    // ================= Phase 1: QKV projection (16 chunks of K=32) ========
    f32x4 acc[12];
    #pragma unroll
    for (int j = 0; j < 12; ++j) acc[j] = fzero;

    const int r = wave * 16 + lr;                  // block-local row
    const float* xr = x + (bB + r) * CC + lq * 8;  // lane's x base

    // W chunk kt (16KB incl pad) -> LDS buf s (2 x 1KB gload_lds per wave)
    auto stageW = [&](int kt, int s) {
        const char* wsrc = (const char*)wpk + kt * 16384;
        char* wdst = smem + s * 16384;
        #pragma unroll
        for (int p = 0; p < 2; ++p) {
            int off = wave * 2048 + p * 1024;
            gload_lds16(wsrc + off + lane * 16, wdst + off);
        }
    };

    #define LOADX(kt, dlo, dhi)                                                \
        {                                                                      \
            const float* p0 = xr + (kt) * 32;                                  \
            asm volatile("global_load_dwordx4 %0, %1, off"                     \
                         : "=&v"(dlo) : "v"(p0) : "memory");                   \
            asm volatile("global_load_dwordx4 %0, %1, off offset:16"           \
                         : "=&v"(dhi) : "v"(p0) : "memory");                   \
        }

    f32x4 x0a, x0b, x1a, x1b, x2a, x2b;   // 3 rotating x slots

    // prologue: W0(2) x0(2) x1(2) = 6 outstanding
    stageW(0, 0);
    LOADX(0, x0a, x0b);
    LOADX(1, x1a, x1b);

    #pragma unroll
    for (int kt = 0; kt < 16; ++kt) {
        const int cur = kt % 3;

        // barrier 1: all waves done reading W buf (kt+1)&1 (iter kt-1)
        __builtin_amdgcn_s_barrier();

        if (kt + 1 < 16) stageW(kt + 1, (kt + 1) & 1);
        if (kt + 2 < 16) {
            const int slot = (kt + 2) % 3;
            if (slot == 0)      LOADX(kt + 2, x0a, x0b)
            else if (slot == 1) LOADX(kt + 2, x1a, x1b)
            else                LOADX(kt + 2, x2a, x2b)
        }

        // wait x(kt) & W(kt): ladder derived from 2W+2x ops/iter
        if (kt <= 13)      asm volatile("s_waitcnt vmcnt(6)" ::: "memory");
        else if (kt == 14) asm volatile("s_waitcnt vmcnt(4)" ::: "memory");
        else               asm volatile("s_waitcnt vmcnt(0)" ::: "memory");
        __builtin_amdgcn_sched_barrier(0);

        // barrier 2: every wave's W(kt) slice visible in LDS
        __builtin_amdgcn_s_barrier();
        __builtin_amdgcn_sched_barrier(0);

        f32x4 alo, ahi;
        if (cur == 0)      { alo = x0a; ahi = x0b; }
        else if (cur == 1) { alo = x1a; ahi = x1b; }
        else               { alo = x2a; ahi = x2b; }
        bf16x8 a;
        a[0] = (short)f2bf(alo[0]); a[1] = (short)f2bf(alo[1]);
        a[2] = (short)f2bf(alo[2]); a[3] = (short)f2bf(alo[3]);
        a[4] = (short)f2bf(ahi[0]); a[5] = (short)f2bf(ahi[1]);
        a[6] = (short)f2bf(ahi[2]); a[7] = (short)f2bf(ahi[3]);

        const ushort* wf = (const ushort*)(smem + (kt & 1) * 16384);
        bf16x8 w[12];
        #pragma unroll
        for (int nt = 0; nt < 12; ++nt)
            w[nt] = *(const bf16x8*)(wf + (nt * 64 + lane) * 8);
        #pragma unroll
        for (int nt = 0; nt < 12; ++nt)
            acc[nt] = __builtin_amdgcn_mfma_f32_16x16x32_bf16(a, w[nt], acc[nt], 0, 0, 0);
    }

    // ---- QKV epilogue: write to virgin attn region (no barrier needed) ----
    {
        const int t0 = wave * 16 + lq * 4;
        #pragma unroll
        for (int nt = 0; nt < 8; ++nt) {           // Q, K: scalar u16
            #pragma unroll
            for (int j = 0; j < 4; ++j) {
                int t = t0 + j;
                int h = (nt & 3) * 16 + lr;
                ushort v = f2bf(acc[nt][j]);
                if (nt < 4) qs[t * 64 + (h ^ ((t & 7) << 3))] = v;
                else        ks[t * 64 + (h ^ ((t & 7) << 3))] = v;
            }
        }
        #pragma unroll
        for (int nt = 8; nt < 12; ++nt) {          // V^T: packed b64
            int h = (nt & 3) * 16 + lr;
            int base = t0 ^ ((h & 7) << 3);        // j bits survive contiguously
            u16x4 v4;
            v4[0] = f2bf(acc[nt][0]); v4[1] = f2bf(acc[nt][1]);
            v4[2] = f2bf(acc[nt][2]); v4[3] = f2bf(acc[nt][3]);
            *(u16x4*)&vst[h * 128 + base] = v4;
        }
    }
    __syncthreads();   // the ONE attention barrier: all QKV visible

    // ================= Phase 2: S = Q K^T, causal softmax =================
    const int row0 = wave * 16;
    f32x4 s[8];
    #pragma unroll
    for (int j = 0; j < 8; ++j) s[j] = fzero;

    #pragma unroll
    for (int kt = 0; kt < 2; ++kt) {
        int h0 = kt * 32 + lq * 8;
        int t  = row0 + lr;
        bf16x8 a = *(const bf16x8*)&qs[t * 64 + (h0 ^ ((t & 7) << 3))];
        bf16x8 kf[8];
        #pragma unroll
        for (int nt = 0; nt < 8; ++nt) {
            int sc = nt * 16 + lr;
            kf[nt] = *(const bf16x8*)&ks[sc * 64 + (h0 ^ ((sc & 7) << 3))];
        }
        #pragma unroll
        for (int nt = 0; nt < 8; ++nt)
            s[nt] = __builtin_amdgcn_mfma_f32_16x16x32_bf16(a, kf[nt], s[nt], 0, 0, 0);
    }

    float rinv[4];
    #pragma unroll
    for (int j = 0; j < 4; ++j) {
        int t = row0 + lq * 4 + j;
        float m = -1e30f;
        #pragma unroll
        for (int nt = 0; nt < 8; ++nt) {
            int sc = nt * 16 + lr;
            float v = s[nt][j] * 0.125f;
            v = (sc <= t) ? v : -1e30f;        // causal mask
            s[nt][j] = v;
            m = fmaxf(m, v);
        }
        m = fmaxf(m, __shfl_xor(m, 1));
        m = fmaxf(m, __shfl_xor(m, 2));
        m = fmaxf(m, __shfl_xor(m, 4));
        m = fmaxf(m, __shfl_xor(m, 8));
        float sum = 0.f;
        #pragma unroll
        for (int nt = 0; nt < 8; ++nt) {
            float p = __expf(s[nt][j] - m);
            s[nt][j] = p;
            sum += p;
        }
        sum += __shfl_xor(sum, 1);
        sum += __shfl_xor(sum, 2);
        sum += __shfl_xor(sum, 4);
        sum += __shfl_xor(sum, 8);
        rinv[j] = 1.0f / sum;                  // deferred normalization
    }

    // ---- P -> LDS (wave-private rows; ps overlays dead W dbuf; no barrier)
    #pragma unroll
    for (int j = 0; j < 4; ++j) {
        int t = row0 + lq * 4 + j;
        #pragma unroll
        for (int nt = 0; nt < 8; ++nt) {
            int sc = nt * 16 + lr;
            ps[t * 128 + (sc ^ ((t & 7) << 3))] = f2bf(s[nt][j]);
        }
    }
    // compiler inserts lgkmcnt for same-wave RAW on ps

    // ================= Phase 3: O = P V =================
    f32x4 o[4];
    #pragma unroll
    for (int j = 0; j < 4; ++j) o[j] = fzero;

    #pragma unroll
    for (int ksv = 0; ksv < 4; ++ksv) {
        int s0 = ksv * 32 + lq * 8;
        int t  = row0 + lr;
        bf16x8 a = *(const bf16x8*)&ps[t * 128 + (s0 ^ ((t & 7) << 3))];
        bf16x8 vf[4];
        #pragma unroll
        for (int nt = 0; nt < 4; ++nt) {
            int h = nt * 16 + lr;
            vf[nt] = *(const bf16x8*)&vst[h * 128 + (s0 ^ ((h & 7) << 3))];
        }
        #pragma unroll
        for (int nt = 0; nt < 4; ++nt)
            o[nt] = __builtin_amdgcn_mfma_f32_16x16x32_bf16(a, vf[nt], o[nt], 0, 0, 0);
    }

    float* ob = out + (size_t)b * (TT * HH);
    #pragma unroll
    for (int nt = 0; nt < 4; ++nt)
        #pragma unroll
        for (int j = 0; j < 4; ++j) {
            int t = row0 + lq * 4 + j;
            int h = nt * 16 + lr;
            ob[t * HH + h] = o[nt][j] * rinv[j];
        }
}

extern "C" void kernel_launch(void* const* d_in, const int* in_sizes, int n_in,
                              void* d_out, int out_size, void* d_ws, size_t ws_size,
                              hipStream_t stream) {
    const float* x  = (const float*)d_in[0];
    const float* wq = (const float*)d_in[1];
    const float* wk = (const float*)d_in[2];
    const float* wv = (const float*)d_in[3];
    float* o = (float*)d_out;
    ushort* wpk = (ushort*)d_ws;    // 16 chunks x 16KB = 256 KB packed W

    (void)in_sizes; (void)n_in; (void)out_size; (void)ws_size;

    wpack_kernel<<<384, 256, 0, stream>>>(wq, wk, wv, wpk);
    attn_fused_kernel<<<512, 512, 0, stream>>>(x, wpk, o);
}